// Round 1
// baseline (133.275 us; speedup 1.0000x reference)
//
#include <hip/hip_runtime.h>
#include <hip/hip_bf16.h>

// Laplace attention: N=2, C=512, S=256, fp32.
// weights[n,c,d] = softmax_d( -sum_s |k[n,d,s]-q[n,c,s]| / 2 )
// out[n,c,s] = sum_d weights[n,c,d] * v[n,d,s]
//
// One block per (n,c) row. 256 threads.

constexpr int N_ = 2;
constexpr int C_ = 512;
constexpr int S_ = 256;

__global__ __launch_bounds__(256)
void laplace_attn_kernel(const float* __restrict__ q,
                         const float* __restrict__ k,
                         const float* __restrict__ v,
                         float* __restrict__ out) {
    const int nc  = blockIdx.x;          // 0..N*C-1
    const int n   = nc / C_;
    const int c   = nc % C_;
    const int tid = threadIdx.x;         // 0..255

    const float* qrow  = q + ((size_t)n * C_ + c) * S_;
    const float* kbase = k + (size_t)n * C_ * S_;
    const float* vbase = v + (size_t)n * C_ * S_;

    __shared__ float q_s[S_];            // 1 KB
    __shared__ float w_s[C_];            // 2 KB (logits -> exp)
    __shared__ float red[16];
    __shared__ float4 acc_s[256];        // 4 KB

    // ---- load q row into LDS (coalesced) ----
    q_s[tid] = qrow[tid];
    __syncthreads();

    // ---- phase 2: logits. thread owns d = tid and tid+256 ----
    const float4* q4 = (const float4*)q_s;
    #pragma unroll
    for (int rep = 0; rep < 2; ++rep) {
        const int d = tid + rep * 256;
        const float4* krow = (const float4*)(kbase + (size_t)d * S_);
        float acc = 0.f;
        #pragma unroll 4
        for (int s4 = 0; s4 < S_ / 4; ++s4) {
            float4 kv = krow[s4];
            float4 qv = q4[s4];
            acc += fabsf(kv.x - qv.x) + fabsf(kv.y - qv.y)
                 + fabsf(kv.z - qv.z) + fabsf(kv.w - qv.w);
        }
        w_s[d] = -acc * 0.5f;
    }
    __syncthreads();

    // ---- softmax over 512 logits ----
    const float w0 = w_s[tid];
    const float w1 = w_s[tid + 256];
    const int wave = tid >> 6;
    const int lane = tid & 63;

    // block max
    float m = fmaxf(w0, w1);
    #pragma unroll
    for (int off = 32; off > 0; off >>= 1)
        m = fmaxf(m, __shfl_down(m, off));
    if (lane == 0) red[wave] = m;
    __syncthreads();
    if (tid == 0)
        red[4] = fmaxf(fmaxf(red[0], red[1]), fmaxf(red[2], red[3]));
    __syncthreads();
    const float M = red[4];

    // exp + block sum
    const float e0 = __expf(w0 - M);
    const float e1 = __expf(w1 - M);
    w_s[tid]       = e0;
    w_s[tid + 256] = e1;
    float ssum = e0 + e1;
    #pragma unroll
    for (int off = 32; off > 0; off >>= 1)
        ssum += __shfl_down(ssum, off);
    if (lane == 0) red[8 + wave] = ssum;
    __syncthreads();
    if (tid == 0)
        red[12] = (red[8] + red[9]) + (red[10] + red[11]);
    __syncthreads();
    const float inv_sum = 1.f / red[12];
    // w_s now holds unnormalized exp; fold inv_sum into epilogue.

    // ---- phase 4: out row = sum_d w[d] * v[d,:] ----
    // 4 groups of 64 lanes; group g covers d in [g*128, g*128+128).
    // Each lane holds s-quad lane*4..lane*4+3 as float4.
    const int g = tid >> 6;   // == wave
    float4 acc = make_float4(0.f, 0.f, 0.f, 0.f);
    const int d0 = g * 128;
    for (int d = d0; d < d0 + 128; ++d) {
        const float wd = w_s[d];
        const float4 vv = ((const float4*)(vbase + (size_t)d * S_))[lane];
        acc.x += wd * vv.x;
        acc.y += wd * vv.y;
        acc.z += wd * vv.z;
        acc.w += wd * vv.w;
    }
    acc_s[tid] = acc;
    __syncthreads();

    if (g == 0) {
        float4 a = acc_s[lane];
        float4 b = acc_s[lane + 64];
        float4 cc = acc_s[lane + 128];
        float4 dd = acc_s[lane + 192];
        float4 tot;
        tot.x = ((a.x + b.x) + (cc.x + dd.x)) * inv_sum;
        tot.y = ((a.y + b.y) + (cc.y + dd.y)) * inv_sum;
        tot.z = ((a.z + b.z) + (cc.z + dd.z)) * inv_sum;
        tot.w = ((a.w + b.w) + (cc.w + dd.w)) * inv_sum;
        ((float4*)(out + ((size_t)n * C_ + c) * S_))[lane] = tot;
    }
}

extern "C" void kernel_launch(void* const* d_in, const int* in_sizes, int n_in,
                              void* d_out, int out_size, void* d_ws, size_t ws_size,
                              hipStream_t stream) {
    const float* q = (const float*)d_in[0];
    const float* k = (const float*)d_in[1];
    const float* v = (const float*)d_in[2];
    float* out = (float*)d_out;

    dim3 grid(N_ * C_);
    dim3 block(256);
    laplace_attn_kernel<<<grid, block, 0, stream>>>(q, k, v, out);
}

// Round 3
// 97.242 us; speedup vs baseline: 1.3705x; 1.3705x over previous
//
#include <hip/hip_runtime.h>
#include <hip/hip_bf16.h>

// Laplace attention: N=2, C=512, S=256, fp32.
// weights[n,c,d] = softmax_d( -sum_s |k[n,d,s]-q[n,c,s]| / 2 )
// out[n,c,s] = sum_d weights[n,c,d] * v[n,d,s]
//
// Main kernel: grid = N * (C/TC) * DSPLIT blocks, 256 threads.
// Each block: TC=4 q-rows vs DH=256 k/v-rows (one d-half), flash-style
// unnormalized partials (o, m, l) to workspace. Combine kernel merges halves.
//
// Key choices:
//  - lane-per-s4 layout: k/v row loads are single coalesced float4 wave-loads.
//  - s-reduction via DPP adds (VALU pipe), NOT __shfl (LDS pipe would bottleneck).
//  - TC=4 c-rows share every loaded k-row -> 4x less L2 traffic.

constexpr int N_ = 2;
constexpr int C_ = 512;
constexpr int S_ = 256;
constexpr int DSPLIT = 2;
constexpr int TC = 4;
constexpr int DH = C_ / DSPLIT;   // 256 d-rows per block
constexpr int NW = 4;             // waves per block
constexpr int DPW = DH / NW;      // 64 d-rows per wave

constexpr size_t PO_SZ = (size_t)N_ * C_ * DSPLIT * S_;  // 524288 floats
constexpr size_t ST_SZ = (size_t)N_ * C_ * DSPLIT;       // 2048 floats

// DPP helpers: ctrl/row_mask must be integer constant expressions -> template params.
template <int CTRL, int ROW_MASK>
__device__ __forceinline__ float dpp_add(float x) {
    // old=0, bound_ctrl=true: invalid/masked lanes contribute 0 to the add.
    int yi = __builtin_amdgcn_update_dpp(0, __float_as_int(x), CTRL, ROW_MASK, 0xf, true);
    return x + __int_as_float(yi);
}
template <int CTRL, int ROW_MASK>
__device__ __forceinline__ float dpp_max(float x) {
    // old=x, bound_ctrl=false: invalid/masked lanes give back x (identity for max).
    int yi = __builtin_amdgcn_update_dpp(__float_as_int(x), __float_as_int(x), CTRL, ROW_MASK, 0xf, false);
    return fmaxf(x, __int_as_float(yi));
}
// Full-wave sum, result broadcast to all lanes.
__device__ __forceinline__ float wave_sum_bcast(float x) {
    x = dpp_add<0x111, 0xf>(x);   // row_shr:1
    x = dpp_add<0x112, 0xf>(x);   // row_shr:2
    x = dpp_add<0x114, 0xf>(x);   // row_shr:4
    x = dpp_add<0x118, 0xf>(x);   // row_shr:8  -> lane15 of each row = row sum
    x = dpp_add<0x142, 0xa>(x);   // row_bcast15 -> lane31/63 accumulate
    x = dpp_add<0x143, 0xc>(x);   // row_bcast31 -> lane63 = total
    return __int_as_float(__builtin_amdgcn_readlane(__float_as_int(x), 63));
}
__device__ __forceinline__ float wave_max_bcast(float x) {
    x = dpp_max<0x111, 0xf>(x);
    x = dpp_max<0x112, 0xf>(x);
    x = dpp_max<0x114, 0xf>(x);
    x = dpp_max<0x118, 0xf>(x);
    x = dpp_max<0x142, 0xa>(x);
    x = dpp_max<0x143, 0xc>(x);
    return __int_as_float(__builtin_amdgcn_readlane(__float_as_int(x), 63));
}

__global__ __launch_bounds__(256)
void laplace_attn_main(const float* __restrict__ q,
                       const float* __restrict__ k,
                       const float* __restrict__ v,
                       float* __restrict__ ws) {
    const int b    = blockIdx.x;            // 0..511
    const int n    = b >> 8;                // 256 blocks per n
    const int r    = b & 255;
    const int half = r & 1;
    const int c0   = (r >> 1) * TC;         // first of TC q-rows
    const int tid  = threadIdx.x;
    const int w    = tid >> 6;              // wave id 0..3
    const int lane = tid & 63;

    const float* kbase = k + (size_t)n * C_ * S_;
    const float* vbase = v + (size_t)n * C_ * S_;

    float* po = ws;                   // [N*C][DSPLIT][S]
    float* pm = ws + PO_SZ;           // [N*C][DSPLIT]
    float* pl = pm + ST_SZ;           // [N*C][DSPLIT]

    __shared__ float4 wt[DH];                 // logits -> exp, per d: (c0..c0+3)  4 KB
    __shared__ float4 accs[NW][TC][64];       // per-wave o partials              16 KB

    // q fragments: lane owns s-quad `lane`
    float4 qv[TC];
    #pragma unroll
    for (int c = 0; c < TC; ++c)
        qv[c] = ((const float4*)(q + ((size_t)n * C_ + c0 + c) * S_))[lane];

    // ---- phase 2: logits for this wave's 64 d-rows ----
    const int dw0 = half * DH + w * DPW;     // global first d-row for this wave
    const float4* k4 = (const float4*)(kbase + (size_t)dw0 * S_);

    #pragma unroll 2
    for (int dd = 0; dd < DPW; ++dd) {
        const float4 kv = k4[dd * 64 + lane];
        float sc[TC];
        #pragma unroll
        for (int c = 0; c < TC; ++c) {
            float ax = fabsf(kv.x - qv[c].x);
            float ay = fabsf(kv.y - qv[c].y);
            float az = fabsf(kv.z - qv[c].z);
            float aw = fabsf(kv.w - qv[c].w);
            sc[c] = wave_sum_bcast((ax + ay) + (az + aw));
        }
        if (lane == 0)
            wt[w * DPW + dd] = make_float4(-0.5f * sc[0], -0.5f * sc[1],
                                           -0.5f * sc[2], -0.5f * sc[3]);
    }
    __syncthreads();

    // ---- softmax (partial, unnormalized): wave w handles c-local = w ----
    {
        const float* wtf = (const float*)wt;
        float x0 = wtf[(lane +   0) * 4 + w];
        float x1 = wtf[(lane +  64) * 4 + w];
        float x2 = wtf[(lane + 128) * 4 + w];
        float x3 = wtf[(lane + 192) * 4 + w];
        float m = fmaxf(fmaxf(x0, x1), fmaxf(x2, x3));
        m = wave_max_bcast(m);
        float e0 = __expf(x0 - m);
        float e1 = __expf(x1 - m);
        float e2 = __expf(x2 - m);
        float e3 = __expf(x3 - m);
        float l = wave_sum_bcast((e0 + e1) + (e2 + e3));
        float* wtm = (float*)wt;
        wtm[(lane +   0) * 4 + w] = e0;
        wtm[(lane +  64) * 4 + w] = e1;
        wtm[(lane + 128) * 4 + w] = e2;
        wtm[(lane + 192) * 4 + w] = e3;
        if (lane == 0) {
            const size_t sidx = ((size_t)n * C_ + c0 + w) * DSPLIT + half;
            pm[sidx] = m;
            pl[sidx] = l;
        }
    }
    __syncthreads();

    // ---- phase 4: o_partial[c] = sum_d e[c][d] * v[d,:] ----
    float4 acc[TC];
    #pragma unroll
    for (int c = 0; c < TC; ++c) acc[c] = make_float4(0.f, 0.f, 0.f, 0.f);

    const float4* v4 = (const float4*)(vbase + (size_t)dw0 * S_);
    #pragma unroll 2
    for (int dd = 0; dd < DPW; ++dd) {
        const float4 vv = v4[dd * 64 + lane];
        const float4 ww = wt[w * DPW + dd];   // broadcast b128
        acc[0].x += ww.x * vv.x; acc[0].y += ww.x * vv.y;
        acc[0].z += ww.x * vv.z; acc[0].w += ww.x * vv.w;
        acc[1].x += ww.y * vv.x; acc[1].y += ww.y * vv.y;
        acc[1].z += ww.y * vv.z; acc[1].w += ww.y * vv.w;
        acc[2].x += ww.z * vv.x; acc[2].y += ww.z * vv.y;
        acc[2].z += ww.z * vv.z; acc[2].w += ww.z * vv.w;
        acc[3].x += ww.w * vv.x; acc[3].y += ww.w * vv.y;
        acc[3].z += ww.w * vv.z; acc[3].w += ww.w * vv.w;
    }
    #pragma unroll
    for (int c = 0; c < TC; ++c) accs[w][c][lane] = acc[c];
    __syncthreads();

    // ---- epilogue: combine 4 waves' partials, write to workspace ----
    {
        const int c = w;            // thread t -> (c = t>>6, s-quad = lane)
        float4 a = accs[0][c][lane];
        float4 bq = accs[1][c][lane];
        float4 cc = accs[2][c][lane];
        float4 dq = accs[3][c][lane];
        float4 o;
        o.x = (a.x + bq.x) + (cc.x + dq.x);
        o.y = (a.y + bq.y) + (cc.y + dq.y);
        o.z = (a.z + bq.z) + (cc.z + dq.z);
        o.w = (a.w + bq.w) + (cc.w + dq.w);
        const size_t oidx = (((size_t)n * C_ + c0 + c) * DSPLIT + half) * S_;
        ((float4*)(po + oidx))[lane] = o;
    }
}

__global__ __launch_bounds__(64)
void laplace_attn_combine(const float* __restrict__ ws,
                          float* __restrict__ out) {
    const int b    = blockIdx.x;      // (n*C + c), 0..1023
    const int lane = threadIdx.x;     // s-quad

    const float* po = ws;
    const float* pm = ws + PO_SZ;
    const float* pl = pm + ST_SZ;

    const float m0 = pm[(size_t)b * 2 + 0];
    const float m1 = pm[(size_t)b * 2 + 1];
    const float l0 = pl[(size_t)b * 2 + 0];
    const float l1 = pl[(size_t)b * 2 + 1];
    const float M  = fmaxf(m0, m1);
    const float a0 = __expf(m0 - M);
    const float a1 = __expf(m1 - M);
    const float inv = 1.f / (a0 * l0 + a1 * l1);

    const float4 o0 = ((const float4*)(po + (size_t)b * 2 * S_))[lane];
    const float4 o1 = ((const float4*)(po + ((size_t)b * 2 + 1) * S_))[lane];
    float4 r;
    r.x = (a0 * o0.x + a1 * o1.x) * inv;
    r.y = (a0 * o0.y + a1 * o1.y) * inv;
    r.z = (a0 * o0.z + a1 * o1.z) * inv;
    r.w = (a0 * o0.w + a1 * o1.w) * inv;
    ((float4*)(out + (size_t)b * S_))[lane] = r;
}

extern "C" void kernel_launch(void* const* d_in, const int* in_sizes, int n_in,
                              void* d_out, int out_size, void* d_ws, size_t ws_size,
                              hipStream_t stream) {
    const float* q = (const float*)d_in[0];
    const float* k = (const float*)d_in[1];
    const float* v = (const float*)d_in[2];
    float* out = (float*)d_out;
    float* ws  = (float*)d_ws;

    laplace_attn_main<<<dim3(N_ * (C_ / TC) * DSPLIT), dim3(256), 0, stream>>>(q, k, v, ws);
    laplace_attn_combine<<<dim3(N_ * C_), dim3(64), 0, stream>>>(ws, out);
}

// Round 4
// 77.291 us; speedup vs baseline: 1.7243x; 1.2581x over previous
//
#include <hip/hip_runtime.h>
#include <hip/hip_bf16.h>

// Laplace attention: N=2, C=512, S=256, fp32.
// weights[n,c,d] = softmax_d( -sum_s |k[n,d,s]-q[n,c,s]| / 2 )
// out[n,c,s] = sum_d weights[n,c,d] * v[n,d,s]
//
// Main kernel (templated on DSPLIT): grid = N*(C/TC)*DSPLIT blocks, 256 thr.
// Each block: TC=4 q-rows vs DH=C/DSPLIT k/v-rows, flash-style unnormalized
// partials (o, m, l) to workspace; combine kernel merges the DSPLIT pieces.
//
// Round-4 changes vs round-3 (which ran 45us @ VALUBusy 36%, Occ 20%):
//  - DSPLIT 2->4: 1024 blocks = 16 waves/CU (occupancy was the bottleneck).
//  - phase 2 processes 2 k-rows per wave (half-wave each, lane owns s-octet):
//    32-lane DPP reduce (5 steps + 2 readlane) amortized over 2 rows.
//  - __launch_bounds__(256,4), deeper load pipelining.

constexpr int N_ = 2;
constexpr int C_ = 512;
constexpr int S_ = 256;
constexpr int TC = 4;
constexpr int NW = 4;             // waves per block

// DPP helpers: ctrl/row_mask are template params (must be constants).
template <int CTRL, int ROW_MASK>
__device__ __forceinline__ float dpp_add(float x) {
    // old=0, bound_ctrl=true: invalid/masked lanes contribute 0.
    int yi = __builtin_amdgcn_update_dpp(0, __float_as_int(x), CTRL, ROW_MASK, 0xf, true);
    return x + __int_as_float(yi);
}
template <int CTRL, int ROW_MASK>
__device__ __forceinline__ float dpp_max(float x) {
    int yi = __builtin_amdgcn_update_dpp(__float_as_int(x), __float_as_int(x), CTRL, ROW_MASK, 0xf, false);
    return fmaxf(x, __int_as_float(yi));
}
// 32-lane-pair reduce: after this, lane31 = sum(l0..31), lane63 = sum(l32..63).
__device__ __forceinline__ float dpp_reduce_halves(float x) {
    x = dpp_add<0x111, 0xf>(x);   // row_shr:1
    x = dpp_add<0x112, 0xf>(x);   // row_shr:2
    x = dpp_add<0x114, 0xf>(x);   // row_shr:4
    x = dpp_add<0x118, 0xf>(x);   // row_shr:8   lane15/31/47/63 = 16-sums
    x = dpp_add<0x142, 0xa>(x);   // row_bcast15 into rows 1,3
    return x;
}
__device__ __forceinline__ float wave_sum_bcast(float x) {
    x = dpp_reduce_halves(x);
    x = dpp_add<0x143, 0xc>(x);   // row_bcast31 -> lane63 = total
    return __int_as_float(__builtin_amdgcn_readlane(__float_as_int(x), 63));
}
__device__ __forceinline__ float wave_max_bcast(float x) {
    x = dpp_max<0x111, 0xf>(x);
    x = dpp_max<0x112, 0xf>(x);
    x = dpp_max<0x114, 0xf>(x);
    x = dpp_max<0x118, 0xf>(x);
    x = dpp_max<0x142, 0xa>(x);
    x = dpp_max<0x143, 0xc>(x);
    return __int_as_float(__builtin_amdgcn_readlane(__float_as_int(x), 63));
}

template <int DSPLIT>
__global__ __launch_bounds__(256, 4)
void laplace_attn_main(const float* __restrict__ q,
                       const float* __restrict__ k,
                       const float* __restrict__ v,
                       float* __restrict__ ws) {
    constexpr int DH  = C_ / DSPLIT;     // d-rows per block
    constexpr int DPW = DH / NW;         // d-rows per wave
    constexpr int E   = DH / 64;         // softmax elems per lane
    constexpr size_t PO_SZ = (size_t)N_ * C_ * DSPLIT * S_;
    constexpr size_t ST_SZ = (size_t)N_ * C_ * DSPLIT;

    const int b      = blockIdx.x;
    constexpr int per_n = (C_ / TC) * DSPLIT;
    const int n    = b / per_n;
    const int r    = b - n * per_n;
    const int half = r % DSPLIT;
    const int c0   = (r / DSPLIT) * TC;
    const int tid  = threadIdx.x;
    const int w    = tid >> 6;
    const int lane = tid & 63;

    const float* kbase = k + (size_t)n * C_ * S_;
    const float* vbase = v + (size_t)n * C_ * S_;

    float* po = ws;                   // [N*C][DSPLIT][S]
    float* pm = ws + PO_SZ;           // [N*C][DSPLIT]
    float* pl = pm + ST_SZ;           // [N*C][DSPLIT]

    __shared__ float4 wt[DH];                 // per d: logits->exp for c0..c0+3
    __shared__ float4 accs[NW][TC][64];       // per-wave o partials (16 KB)

    // ---- q octets in registers: lane owns s = j*8 .. j*8+7 (j = lane&31) ----
    const int h = lane >> 5;                 // which of the 2 rows this lane serves
    const int j = lane & 31;                 // s-octet index
    float4 qa[TC], qb[TC];
    #pragma unroll
    for (int c = 0; c < TC; ++c) {
        const float4* qr = (const float4*)(q + ((size_t)n * C_ + c0 + c) * S_);
        qa[c] = qr[2 * j];
        qb[c] = qr[2 * j + 1];
    }

    const int dw0 = half * DH + w * DPW;     // first global d-row for this wave
    const float* kw = kbase + (size_t)dw0 * S_;

    // ---- phase 2: logits, 2 rows per pass ----
    #pragma unroll 2
    for (int g2 = 0; g2 < DPW; g2 += 2) {
        const float4* rp = (const float4*)(kw + (size_t)(g2 + h) * S_ + j * 8);
        const float4 ka = rp[0];
        const float4 kb = rp[1];
        float s0[TC], s1[TC];
        #pragma unroll
        for (int c = 0; c < TC; ++c) {
            float p = fabsf(ka.x - qa[c].x) + fabsf(ka.y - qa[c].y)
                    + fabsf(ka.z - qa[c].z) + fabsf(ka.w - qa[c].w)
                    + fabsf(kb.x - qb[c].x) + fabsf(kb.y - qb[c].y)
                    + fabsf(kb.z - qb[c].z) + fabsf(kb.w - qb[c].w);
            p = dpp_reduce_halves(p);
            s0[c] = __int_as_float(__builtin_amdgcn_readlane(__float_as_int(p), 31));
            s1[c] = __int_as_float(__builtin_amdgcn_readlane(__float_as_int(p), 63));
        }
        if (lane == 0) {
            wt[w * DPW + g2]     = make_float4(-0.5f * s0[0], -0.5f * s0[1],
                                               -0.5f * s0[2], -0.5f * s0[3]);
            wt[w * DPW + g2 + 1] = make_float4(-0.5f * s1[0], -0.5f * s1[1],
                                               -0.5f * s1[2], -0.5f * s1[3]);
        }
    }
    __syncthreads();

    // ---- softmax (partial, unnormalized): wave w handles c-local = w ----
    {
        const float* wtf = (const float*)wt;
        float x[E];
        #pragma unroll
        for (int e = 0; e < E; ++e) x[e] = wtf[(lane + 64 * e) * 4 + w];
        float m = x[0];
        #pragma unroll
        for (int e = 1; e < E; ++e) m = fmaxf(m, x[e]);
        m = wave_max_bcast(m);
        float es[E], l = 0.f;
        #pragma unroll
        for (int e = 0; e < E; ++e) { es[e] = __expf(x[e] - m); l += es[e]; }
        l = wave_sum_bcast(l);
        float* wtm = (float*)wt;
        #pragma unroll
        for (int e = 0; e < E; ++e) wtm[(lane + 64 * e) * 4 + w] = es[e];
        if (lane == 0) {
            const size_t sidx = ((size_t)n * C_ + c0 + w) * DSPLIT + half;
            pm[sidx] = m;
            pl[sidx] = l;
        }
    }
    __syncthreads();

    // ---- phase 4: o_partial[c] = sum_d e[c][d] * v[d,:] (lane owns s-quad) ----
    float4 acc[TC];
    #pragma unroll
    for (int c = 0; c < TC; ++c) acc[c] = make_float4(0.f, 0.f, 0.f, 0.f);

    const float4* v4 = (const float4*)(vbase + (size_t)dw0 * S_);
    #pragma unroll 4
    for (int dd = 0; dd < DPW; ++dd) {
        const float4 vv = v4[dd * 64 + lane];
        const float4 ww = wt[w * DPW + dd];   // uniform b128 broadcast
        acc[0].x += ww.x * vv.x; acc[0].y += ww.x * vv.y;
        acc[0].z += ww.x * vv.z; acc[0].w += ww.x * vv.w;
        acc[1].x += ww.y * vv.x; acc[1].y += ww.y * vv.y;
        acc[1].z += ww.y * vv.z; acc[1].w += ww.y * vv.w;
        acc[2].x += ww.z * vv.x; acc[2].y += ww.z * vv.y;
        acc[2].z += ww.z * vv.z; acc[2].w += ww.z * vv.w;
        acc[3].x += ww.w * vv.x; acc[3].y += ww.w * vv.y;
        acc[3].z += ww.w * vv.z; acc[3].w += ww.w * vv.w;
    }
    #pragma unroll
    for (int c = 0; c < TC; ++c) accs[w][c][lane] = acc[c];
    __syncthreads();

    // ---- epilogue: combine 4 waves' partials, write workspace ----
    {
        const int c = w;
        float4 a  = accs[0][c][lane];
        float4 bq = accs[1][c][lane];
        float4 cc = accs[2][c][lane];
        float4 dq = accs[3][c][lane];
        float4 o;
        o.x = (a.x + bq.x) + (cc.x + dq.x);
        o.y = (a.y + bq.y) + (cc.y + dq.y);
        o.z = (a.z + bq.z) + (cc.z + dq.z);
        o.w = (a.w + bq.w) + (cc.w + dq.w);
        const size_t oidx = (((size_t)n * C_ + c0 + c) * DSPLIT + half) * S_;
        ((float4*)(po + oidx))[lane] = o;
    }
}

template <int DSPLIT>
__global__ __launch_bounds__(64)
void laplace_attn_combine(const float* __restrict__ ws,
                          float* __restrict__ out) {
    constexpr size_t PO_SZ = (size_t)N_ * C_ * DSPLIT * S_;
    constexpr size_t ST_SZ = (size_t)N_ * C_ * DSPLIT;
    const int b    = blockIdx.x;      // (n*C + c)
    const int lane = threadIdx.x;     // s-quad

    const float* po = ws;
    const float* pm = ws + PO_SZ;
    const float* pl = pm + ST_SZ;

    float m[DSPLIT], l[DSPLIT];
    #pragma unroll
    for (int hh = 0; hh < DSPLIT; ++hh) {
        m[hh] = pm[(size_t)b * DSPLIT + hh];
        l[hh] = pl[(size_t)b * DSPLIT + hh];
    }
    float M = m[0];
    #pragma unroll
    for (int hh = 1; hh < DSPLIT; ++hh) M = fmaxf(M, m[hh]);
    float den = 0.f, a[DSPLIT];
    #pragma unroll
    for (int hh = 0; hh < DSPLIT; ++hh) { a[hh] = __expf(m[hh] - M); den += a[hh] * l[hh]; }
    const float inv = 1.f / den;

    float4 rsum = make_float4(0.f, 0.f, 0.f, 0.f);
    #pragma unroll
    for (int hh = 0; hh < DSPLIT; ++hh) {
        const float4 o = ((const float4*)(po + ((size_t)b * DSPLIT + hh) * S_))[lane];
        rsum.x += a[hh] * o.x;
        rsum.y += a[hh] * o.y;
        rsum.z += a[hh] * o.z;
        rsum.w += a[hh] * o.w;
    }
    float4 rr;
    rr.x = rsum.x * inv; rr.y = rsum.y * inv;
    rr.z = rsum.z * inv; rr.w = rsum.w * inv;
    ((float4*)(out + (size_t)b * S_))[lane] = rr;
}

extern "C" void kernel_launch(void* const* d_in, const int* in_sizes, int n_in,
                              void* d_out, int out_size, void* d_ws, size_t ws_size,
                              hipStream_t stream) {
    const float* q = (const float*)d_in[0];
    const float* k = (const float*)d_in[1];
    const float* v = (const float*)d_in[2];
    float* out = (float*)d_out;
    float* ws  = (float*)d_ws;

    constexpr size_t NEED4 =
        ((size_t)N_ * C_ * 4 * S_ + 2 * (size_t)N_ * C_ * 4) * sizeof(float);

    if (ws_size >= NEED4) {
        laplace_attn_main<4><<<dim3(N_ * (C_ / TC) * 4), dim3(256), 0, stream>>>(q, k, v, ws);
        laplace_attn_combine<4><<<dim3(N_ * C_), dim3(64), 0, stream>>>(ws, out);
    } else {
        laplace_attn_main<2><<<dim3(N_ * (C_ / TC) * 2), dim3(256), 0, stream>>>(q, k, v, ws);
        laplace_attn_combine<2><<<dim3(N_ * C_), dim3(64), 0, stream>>>(ws, out);
    }
}